// Round 10
// baseline (83.752 us; speedup 1.0000x reference)
//
#include <hip/hip_runtime.h>
#include <cmath>

typedef _Float16 half8 __attribute__((ext_vector_type(8)));
typedef float f32x4 __attribute__((ext_vector_type(4)));

namespace {
constexpr int BB   = 64;
constexpr int TT   = 1002;
constexpr int DD   = 8;
constexpr int HH   = 64;
constexpr int LAGS = 2;
constexpr int NW   = TT - LAGS;          // 1000
constexpr int FIN  = LAGS * DD + 1;      // 17
constexpr int NTOT = BB * NW;            // 64000
constexpr int GXB  = 16;                 // x-blocks (64 windows each)
constexpr int NSTR = GXB * 4;            // 64 strips of 16 windows per (b,d)

// output layout (flat, return order)
constexpr int RES_OFF = 0;
constexpr int LOG_OFF = NTOT * DD;
constexpr int HJ_OFF  = LOG_OFF + BB;

// prepacked A-fragment arrays in d_ws (f16 units).
// A-frag layout per (mt,kc): lane holds A[m][k], m = mt*16 + (lane&15),
// k = kc*32 + (lane>>4)*8 + j, j=0..7  -> [mt][kc][lane][8] contiguous.
constexpr int SZ_A0F = 4 * 1 * 64 * 8;   // fwd L0: A[h][f], K=32 (pad f>=17 -> 0)
constexpr int SZ_AH  = 4 * 2 * 64 * 8;   // 64x64 matrices, K=64
constexpr int SZ_A0T = 2 * 2 * 64 * 8;   // g-step: A[f][h], M=32 (pad f>=17 -> 0)
constexpr int OA0F = 0;
constexpr int OA1F = OA0F + DD * SZ_A0F; // W1 fwd
constexpr int OA2F = OA1F + DD * SZ_AH;  // W2 fwd
constexpr int OA2T = OA2F + DD * SZ_AH;  // W2^T (v1 step)
constexpr int OA1T = OA2T + DD * SZ_AH;  // W1^T (v0 step)
constexpr int OA0T = OA1T + DD * SZ_AH;  // W0^T (g step)
constexpr int WTOT = OA0T + DD * SZ_A0T; // 163840 f16 = 320 KB
}

// packed f32->f16 conversion (v_cvt_pkrtz_f16_f32): 1 inst / 2 elements.
__device__ __forceinline__ unsigned int pku(float a, float b) {
    return __builtin_bit_cast(unsigned int, __builtin_amdgcn_cvt_pkrtz(a, b));
}

// same-wave LDS fence (all activation traffic is wave-private in this version).
#define LFENCE() asm volatile("s_waitcnt lgkmcnt(0)" ::: "memory")

// Prepack all weights into per-lane MFMA A-fragments (f16).
__global__ void setup_weights(const float* __restrict__ W0, const float* __restrict__ W1,
                              const float* __restrict__ W2, _Float16* __restrict__ wsp)
{
    for (int i = blockIdx.x * blockDim.x + threadIdx.x; i < WTOT;
         i += gridDim.x * blockDim.x) {
        float val;
        if (i < OA1F) {          // A0F: A[m=h][k=f] = W0[d,m,k], K=32 padded
            int j = i - OA0F, d = j / SZ_A0F, r = j % SZ_A0F;
            int mt = r / 512, r2 = r % 512, lane = r2 / 8, jj = r2 % 8;
            int m = mt * 16 + (lane & 15), k = (lane >> 4) * 8 + jj;
            val = (k < FIN) ? W0[((size_t)d * HH + m) * FIN + k] : 0.0f;
        } else if (i < OA2F) {   // A1F: A[m][k] = W1[d,m,k]
            int j = i - OA1F, d = j / SZ_AH, r = j % SZ_AH;
            int mt = r / 1024, r2 = r % 1024, kc = r2 / 512, r3 = r2 % 512;
            int lane = r3 / 8, jj = r3 % 8;
            int m = mt * 16 + (lane & 15), k = kc * 32 + (lane >> 4) * 8 + jj;
            val = W1[((size_t)d * HH + m) * HH + k];
        } else if (i < OA2T) {   // A2F: A[m][k] = W2[d,m,k]
            int j = i - OA2F, d = j / SZ_AH, r = j % SZ_AH;
            int mt = r / 1024, r2 = r % 1024, kc = r2 / 512, r3 = r2 % 512;
            int lane = r3 / 8, jj = r3 % 8;
            int m = mt * 16 + (lane & 15), k = kc * 32 + (lane >> 4) * 8 + jj;
            val = W2[((size_t)d * HH + m) * HH + k];
        } else if (i < OA1T) {   // A2T: A[m=h'][k=g] = W2[d,k,m]
            int j = i - OA2T, d = j / SZ_AH, r = j % SZ_AH;
            int mt = r / 1024, r2 = r % 1024, kc = r2 / 512, r3 = r2 % 512;
            int lane = r3 / 8, jj = r3 % 8;
            int m = mt * 16 + (lane & 15), k = kc * 32 + (lane >> 4) * 8 + jj;
            val = W2[((size_t)d * HH + k) * HH + m];
        } else if (i < OA0T) {   // A1T: A[m=h][k=h'] = W1[d,k,m]
            int j = i - OA1T, d = j / SZ_AH, r = j % SZ_AH;
            int mt = r / 1024, r2 = r % 1024, kc = r2 / 512, r3 = r2 % 512;
            int lane = r3 / 8, jj = r3 % 8;
            int m = mt * 16 + (lane & 15), k = kc * 32 + (lane >> 4) * 8 + jj;
            val = W1[((size_t)d * HH + k) * HH + m];
        } else {                 // A0T: A[m=f][k=h] = W0[d,k,m], M=32 padded
            int j = i - OA0T, d = j / SZ_A0T, r = j % SZ_A0T;
            int mt = r / 1024, r2 = r % 1024, kc = r2 / 512, r3 = r2 % 512;
            int lane = r3 / 8, jj = r3 % 8;
            int m = mt * 16 + (lane & 15), k = kc * 32 + (lane >> 4) * 8 + jj;
            val = (m < FIN) ? W0[((size_t)d * HH + k) * FIN + m] : 0.0f;
        }
        wsp[i] = (_Float16)val;
    }
}

// swizzled LDS byte address for activation rows (128B each):
// XOR bits 4-6 with (n&7) -> conflict-light reads and writes.
__device__ __forceinline__ int swb(int n, int byteoff) {
    return n * 128 + (byteoff ^ ((n & 7) << 4));
}

// N-split, barrier-free: block = (window-tile, b, d), 256 threads = 4 waves.
// Wave wv owns windows w0+wv*16 .. +15 and the FULL M=64 of every GEMM
// (C[4] f32x4 = 16 VGPR). Its 16 LDS rows (2KB) are private -> no
// __syncthreads anywhere; stage ordering is same-wave lgkmcnt. Weights are
// intentionally NOT hoisted (round-9 evidence: allocator targets 64 VGPR and
// un-hoists anyway) -- each stage re-loads its A-fragments from the L2-hot
// 320KB pack. LDS addresses computed once.
__global__ __launch_bounds__(256, 4) void fused_mlp(
    const float* __restrict__ x,
    const float* __restrict__ b0, const float* __restrict__ a0,
    const float* __restrict__ b1, const float* __restrict__ a1,
    const float* __restrict__ b2, const float* __restrict__ a2,
    const float* __restrict__ W3, const float* __restrict__ b3,
    const _Float16* __restrict__ wsp,
    float* __restrict__ out, float* __restrict__ partials)
{
    const int b   = blockIdx.y;    // 0..BB-1
    const int d   = blockIdx.z;    // 0..DD-1
    const int tid = threadIdx.x;
    const int wv  = __builtin_amdgcn_readfirstlane(tid >> 6);  // 0..3
    const int t   = tid & 63;
    const int hi  = t >> 4, lo = t & 15;
    const int w0s = blockIdx.x * 64 + wv * 16;   // this wave's window base
    const int n   = w0s + lo;                    // this lane's window
    const bool nv = (n < NW);
    const int nrow = wv * 16 + lo;               // private LDS row

    __shared__ __align__(16) unsigned char Xs[64 * 128];  // 8KB, 2KB per wave

    // hoisted LDS addresses (loop-invariant per thread)
    int rdA0 = swb(nrow, hi * 16);          // B-frag read, kc=0
    int rdA1 = swb(nrow, 64 + hi * 16);     // B-frag read, kc=1
    int wrA[4];
    #pragma unroll
    for (int mt = 0; mt < 4; ++mt) wrA[mt] = swb(nrow, mt * 32 + hi * 8);

    // ---- stage this wave's 16 input rows (lanes hi==0 only) ----
    if (hi == 0) {
        const int w = min(w0s + lo, NW - 1);
        const float* xr = x + ((size_t)b * TT + w) * DD;
        f32x4 x0 = *(const f32x4*)(xr + 0);
        f32x4 x1 = *(const f32x4*)(xr + 4);
        f32x4 x2 = *(const f32x4*)(xr + 8);
        f32x4 x3 = *(const f32x4*)(xr + 12);
        float xl = xr[2 * DD + d];
        uint4 q0, q1, qz, zz;
        q0.x = pku(x0[0], x0[1]); q0.y = pku(x0[2], x0[3]);
        q0.z = pku(x1[0], x1[1]); q0.w = pku(x1[2], x1[3]);
        q1.x = pku(x2[0], x2[1]); q1.y = pku(x2[2], x2[3]);
        q1.z = pku(x3[0], x3[1]); q1.w = pku(x3[2], x3[3]);
        qz.x = pku(xl, 0.f); qz.y = 0u; qz.z = 0u; qz.w = 0u;
        zz.x = 0u; zz.y = 0u; zz.z = 0u; zz.w = 0u;
        *(uint4*)&Xs[swb(nrow, 0)]  = q0;
        *(uint4*)&Xs[swb(nrow, 16)] = q1;
        *(uint4*)&Xs[swb(nrow, 32)] = qz;   // k 16..23 (f16 elem + zeros)
        *(uint4*)&Xs[swb(nrow, 48)] = zz;   // k 24..31 zero (L0 pads)
    }
    LFENCE();

    const float A0v = a0[d], A1v = a1[d], A2v = a2[d];
    f32x4 C[4];   // [mt]: row h = mt*16 + hi*4 + r, col n = lo

    // K=64 GEMM over full M=64 (A reloaded from L2-hot pack; B private LDS)
    auto gemmK64 = [&](const _Float16* apk, const float* bias) {
        if (bias) {
            #pragma unroll
            for (int mt = 0; mt < 4; ++mt)
                C[mt] = *(const f32x4*)(bias + mt * 16 + hi * 4);
        } else {
            #pragma unroll
            for (int mt = 0; mt < 4; ++mt) {
                C[mt][0] = 0.f; C[mt][1] = 0.f; C[mt][2] = 0.f; C[mt][3] = 0.f;
            }
        }
        {
            half8 Bv = *(const half8*)&Xs[rdA0];
            #pragma unroll
            for (int mt = 0; mt < 4; ++mt) {
                half8 a = *(const half8*)(apk + (size_t)((mt * 2 + 0) * 64 + t) * 8);
                C[mt] = __builtin_amdgcn_mfma_f32_16x16x32_f16(a, Bv, C[mt], 0, 0, 0);
            }
        }
        {
            half8 Bv = *(const half8*)&Xs[rdA1];
            #pragma unroll
            for (int mt = 0; mt < 4; ++mt) {
                half8 a = *(const half8*)(apk + (size_t)((mt * 2 + 1) * 64 + t) * 8);
                C[mt] = __builtin_amdgcn_mfma_f32_16x16x32_f16(a, Bv, C[mt], 0, 0, 0);
            }
        }
    };

    // store C (f16) into this wave's private rows as next-layer K
    auto storeC = [&]() {
        #pragma unroll
        for (int mt = 0; mt < 4; ++mt) {
            uint2 pk;
            pk.x = pku(C[mt][0], C[mt][1]);
            pk.y = pku(C[mt][2], C[mt][3]);
            *(uint2*)&Xs[wrA[mt]] = pk;
        }
    };

    unsigned int m0 = 0u, m1 = 0u, m2 = 0u;   // 16-bit masks: bit = mt*4 + r
    auto prelu = [&](float slope, unsigned int& mask) {
        #pragma unroll
        for (int mt = 0; mt < 4; ++mt)
            #pragma unroll
            for (int r = 0; r < 4; ++r) {
                float z = C[mt][r];
                if (z > 0.0f) mask |= 1u << (mt * 4 + r);
                C[mt][r] = fmaxf(z, slope * z);  // slope=0.25 in [0,1]
            }
    };
    auto bwd_mask = [&](float slope, unsigned int mask) {
        #pragma unroll
        for (int mt = 0; mt < 4; ++mt)
            #pragma unroll
            for (int r = 0; r < 4; ++r)
                if (!((mask >> (mt * 4 + r)) & 1u))
                    C[mt][r] *= slope;
    };

    // ================= forward =================
    // layer 0: K=32 (kc=0 only), A0F frag layout [mt][lane][8]
    {
        const _Float16* apk = wsp + OA0F + (size_t)d * SZ_A0F;
        #pragma unroll
        for (int mt = 0; mt < 4; ++mt)
            C[mt] = *(const f32x4*)(b0 + d * HH + mt * 16 + hi * 4);
        half8 Bv = *(const half8*)&Xs[rdA0];
        #pragma unroll
        for (int mt = 0; mt < 4; ++mt) {
            half8 a = *(const half8*)(apk + (size_t)(mt * 64 + t) * 8);
            C[mt] = __builtin_amdgcn_mfma_f32_16x16x32_f16(a, Bv, C[mt], 0, 0, 0);
        }
    }
    prelu(A0v, m0); storeC(); LFENCE();

    gemmK64(wsp + OA1F + (size_t)d * SZ_AH, b1 + d * HH);
    prelu(A1v, m1); storeC(); LFENCE();

    gemmK64(wsp + OA2F + (size_t)d * SZ_AH, b2 + d * HH);
    prelu(A2v, m2);   // h2 stays in C for the output dot

    // ---- output dot: wave holds ALL h for its 16 windows ----
    f32x4 w3v[4];
    #pragma unroll
    for (int mt = 0; mt < 4; ++mt)
        w3v[mt] = *(const f32x4*)(W3 + d * HH + mt * 16 + hi * 4);
    {
        float s = 0.0f;
        #pragma unroll
        for (int mt = 0; mt < 4; ++mt)
            #pragma unroll
            for (int r = 0; r < 4; ++r)
                s = fmaf(w3v[mt][r], C[mt][r], s);
        s += __shfl_xor(s, 16);
        s += __shfl_xor(s, 32);
        if (hi == 0 && nv)
            out[RES_OFF + ((size_t)b * NW + n) * DD + d] = s + b3[d];
    }

    // ================= backward =================
    // v2[h][n] = w3[h] * d2(h,n)
    #pragma unroll
    for (int mt = 0; mt < 4; ++mt)
        #pragma unroll
        for (int r = 0; r < 4; ++r) {
            float dv = ((m2 >> (mt * 4 + r)) & 1u) ? 1.0f : A2v;
            C[mt][r] = w3v[mt][r] * dv;
        }
    storeC(); LFENCE();

    gemmK64(wsp + OA2T + (size_t)d * SZ_AH, nullptr);
    bwd_mask(A1v, m1); storeC(); LFENCE();

    gemmK64(wsp + OA1T + (size_t)d * SZ_AH, nullptr);
    bwd_mask(A0v, m0); storeC(); LFENCE();

    // ---- g = W0^T @ v0 : M=32 (f rows), this wave's 16 cols ----
    f32x4 G[2];
    {
        const _Float16* apk = wsp + OA0T + (size_t)d * SZ_A0T;
        #pragma unroll
        for (int mt = 0; mt < 2; ++mt) {
            G[mt][0] = 0.f; G[mt][1] = 0.f; G[mt][2] = 0.f; G[mt][3] = 0.f;
        }
        {
            half8 Bv = *(const half8*)&Xs[rdA0];
            #pragma unroll
            for (int mt = 0; mt < 2; ++mt) {
                half8 a = *(const half8*)(apk + (size_t)((mt * 2 + 0) * 64 + t) * 8);
                G[mt] = __builtin_amdgcn_mfma_f32_16x16x32_f16(a, Bv, G[mt], 0, 0, 0);
            }
        }
        {
            half8 Bv = *(const half8*)&Xs[rdA1];
            #pragma unroll
            for (int mt = 0; mt < 2; ++mt) {
                half8 a = *(const half8*)(apk + (size_t)((mt * 2 + 1) * 64 + t) * 8);
                G[mt] = __builtin_amdgcn_mfma_f32_16x16x32_f16(a, Bv, G[mt], 0, 0, 0);
            }
        }
    }

    // hist_jac: f = hi*4 + r (rows 0..15 = G[0]), n = this lane's window
    if (nv)
        *(f32x4*)(out + HJ_OFF + ((size_t)d * NTOT + (size_t)b * NW + n) * 16
                  + hi * 4) = G[0];

    // log|g[16]|: f=16 -> G[1] reg 0 on hi==0 lanes
    {
        float ld = (hi == 0 && nv) ? __logf(fabsf(G[1][0])) : 0.0f;
        #pragma unroll
        for (int off = 32; off > 0; off >>= 1) ld += __shfl_down(ld, off);
        if (t == 0) partials[((b * DD + d) * NSTR) + blockIdx.x * 4 + wv] = ld;
    }
}

__global__ void reduce_log(const float* __restrict__ partials, float* __restrict__ out)
{
    const int b = threadIdx.x;   // 64 threads
    float s = 0.0f;
    for (int i = 0; i < DD * NSTR; ++i) s += partials[b * (DD * NSTR) + i];
    out[LOG_OFF + b] = s;
}

extern "C" void kernel_launch(void* const* d_in, const int* in_sizes, int n_in,
                              void* d_out, int out_size, void* d_ws, size_t ws_size,
                              hipStream_t stream)
{
    const float* x  = (const float*)d_in[0];
    const float* W0 = (const float*)d_in[1];
    const float* b0 = (const float*)d_in[2];
    const float* a0 = (const float*)d_in[3];
    const float* W1 = (const float*)d_in[4];
    const float* b1 = (const float*)d_in[5];
    const float* a1 = (const float*)d_in[6];
    const float* W2 = (const float*)d_in[7];
    const float* b2 = (const float*)d_in[8];
    const float* a2 = (const float*)d_in[9];
    const float* W3 = (const float*)d_in[10];
    const float* b3 = (const float*)d_in[11];

    float*     out      = (float*)d_out;
    _Float16*  wsp      = (_Float16*)d_ws;
    float*     partials = (float*)((char*)d_ws + (size_t)WTOT * 2);  // 32768 floats

    setup_weights<<<160, 1024, 0, stream>>>(W0, W1, W2, wsp);

    dim3 grid(GXB, BB, DD);   // 16 x 64 x 8 = 8192 blocks x 4 independent waves
    fused_mlp<<<grid, 256, 0, stream>>>(x, b0, a0, b1, a1, b2, a2, W3, b3,
                                        wsp, out, partials);
    reduce_log<<<1, BB, 0, stream>>>(partials, out);
}